// Round 5
// baseline (2301.765 us; speedup 1.0000x reference)
//
#include <hip/hip_runtime.h>

#define BATCH 1024
#define CDIM  512
#define DDIM  256
#define KCB   8192
#define HD    512
#define G3    1536
#define TSTEPS 8

// ---------------- workspace layout (float offsets) ----------------
#define WS_CB    ((size_t)0)          // [K,D]
#define WS_EW    ((size_t)2097152)    // [K,D]
#define WS_CSR   ((size_t)4194304)    // ints: list[1024] | base[8192] | cnts[8192]
#define WS_SM    ((size_t)6291456)    // [B,C]
#define WS_H     ((size_t)6815744)    // [B,HD]
#define WS_PREV  ((size_t)7340032)    // [B,D]
#define WS_Z     ((size_t)7602176)    // [B,D]
#define WS_GX    ((size_t)7864320)    // [B,3HD]
#define WS_GH    ((size_t)9437184)    // [B,3HD]
#define WS_PIN   ((size_t)12058624)   // [B,1024]
#define WS_H1    ((size_t)13107200)   // [B,HD]
#define WS_CS    ((size_t)13631488)   // [K]
#define WS_CBSQ  ((size_t)13639680)   // [K]
#define WS_SZZ   ((size_t)13647872)   // [B]
#define WS_NT    ((size_t)13657088)   // [1]+pad
#define WS_LOSS  ((size_t)13657090)   // [1]+pad
#define WS_IDX   ((size_t)13657092)   // [B] ints
#define WS_ROWK  ((size_t)13658116)   // [B] u64 (8B-aligned)
#define WS_WGWB  ((size_t)13660164)   // [1024,512] interleaved (Wg[c],Wb[c]) rows
#define WS_BGBB  ((size_t)14184452)   // [1024] interleaved (bg[c],bb[c])

// ---------------- output layout (f32 elements) ----------------
#define OUT_HF    ((size_t)0)
#define OUT_CODES ((size_t)524288)
#define OUT_IDX   ((size_t)2621440)
#define OUT_ZC    ((size_t)2629632)
#define OUT_LOSS  ((size_t)4726784)

// order-preserving map of f32 bits; col in low 32 bits -> ties pick lowest col
static __device__ __forceinline__ unsigned long long key32(float s, int col) {
  unsigned int u = __float_as_uint(s);
  u = (u & 0x80000000u) ? ~u : (u | 0x80000000u);
  return (((unsigned long long)u) << 32) | (unsigned long long)(unsigned int)col;
}

// numpy pairwise_sum for n=128 block: 8 accumulators, tree combine
static __device__ __forceinline__ float pw128(const float* a) {
  float r0=a[0],r1=a[1],r2=a[2],r3=a[3],r4=a[4],r5=a[5],r6=a[6],r7=a[7];
  for (int i = 8; i < 128; i += 8) {
    r0+=a[i+0]; r1+=a[i+1]; r2+=a[i+2]; r3+=a[i+3];
    r4+=a[i+4]; r5+=a[i+5]; r6+=a[i+6]; r7+=a[i+7];
  }
  return ((r0+r1)+(r2+r3))+((r4+r5)+(r6+r7));
}

// ============================================================================
// SINGLE-buffered fp32 GEMM engine with CHUNKED fragments.
// A/B on MI355X (r0 vs r4, same 64x64 tile): single-buffer 64.7us @36VGPR/48%occ
// beats double-buffer 70us @84VGPR/27%occ — TLP > ILP prefetch for these tiles.
// Loop: load(regs) -> sync -> store(LDS) -> sync -> compute.
// Per output element the accumulation is an fmaf chain in ascending-k order
// over the FULL K — bitwise identical to all previous rounds.
// ============================================================================
template<int BM,int BN,int BK,int TM,int TN>
__device__ __forceinline__ void gemm_engine(
    const float* __restrict__ A, int lda,
    const float* __restrict__ B, int ldb, int K,
    int m0, int n0, int tid,
    float* __restrict__ As, float* __restrict__ Bs,
    float (&acc)[TM][TN])
{
  constexpr int NT = 256;
  constexpr int K4 = BK/4;
  constexpr int LA = (BM*BK)/(4*NT);
  constexpr int LB = (BN*BK)/(4*NT);
  constexpr int SA = BM+4;
  constexpr int SB = BN+4;
  constexpr int ACW = (TM % 4 == 0) ? 4 : 2;
  constexpr int BCW = (TN % 4 == 0) ? 4 : 2;
  constexpr int ANC = TM/ACW;
  constexpr int BNC = TN/BCW;
  constexpr int AR  = BM/ANC;     // row offset between A chunks
  constexpr int BR  = BN/BNC;     // col offset between B chunks
  static_assert((BM/TM)*(BN/TN) == NT, "256 threads");
  static_assert(LA >= 1 && LB >= 1, "stage width");

  const int tx = tid % (BN/TN);
  const int ty = tid / (BN/TN);

  int arow[LA], ak4[LA], brow[LB], bk4[LB];
#pragma unroll
  for (int l=0;l<LA;++l){ int f=l*NT+tid; arow[l]=f/K4; ak4[l]=f%K4; }
#pragma unroll
  for (int l=0;l<LB;++l){ int f=l*NT+tid; brow[l]=f/K4; bk4[l]=f%K4; }

  for (int k0 = 0; k0 < K; k0 += BK) {
    float4 ra[LA], rb[LB];
#pragma unroll
    for (int l=0;l<LA;++l) ra[l] = *(const float4*)(A + (size_t)(m0+arow[l])*lda + k0 + ak4[l]*4);
#pragma unroll
    for (int l=0;l<LB;++l) rb[l] = *(const float4*)(B + (size_t)(n0+brow[l])*ldb + k0 + bk4[l]*4);
    __syncthreads();    // prior compute done reading LDS (loads in flight meanwhile)
#pragma unroll
    for (int l=0;l<LA;++l){ int kb=ak4[l]*4, r=arow[l];
      As[(kb+0)*SA+r]=ra[l].x; As[(kb+1)*SA+r]=ra[l].y; As[(kb+2)*SA+r]=ra[l].z; As[(kb+3)*SA+r]=ra[l].w; }
#pragma unroll
    for (int l=0;l<LB;++l){ int kb=bk4[l]*4, r=brow[l];
      Bs[(kb+0)*SB+r]=rb[l].x; Bs[(kb+1)*SB+r]=rb[l].y; Bs[(kb+2)*SB+r]=rb[l].z; Bs[(kb+3)*SB+r]=rb[l].w; }
    __syncthreads();
#pragma unroll
    for (int kk=0;kk<BK;++kk){
      float af[TM], bf[TN];
#pragma unroll
      for (int c=0;c<ANC;++c){
        if constexpr (ACW == 4) {
          float4 v = *(const float4*)&As[kk*SA + c*AR + ty*4];
          af[c*4+0]=v.x; af[c*4+1]=v.y; af[c*4+2]=v.z; af[c*4+3]=v.w;
        } else {
          float2 v = *(const float2*)&As[kk*SA + c*AR + ty*2];
          af[c*2+0]=v.x; af[c*2+1]=v.y;
        }
      }
#pragma unroll
      for (int c=0;c<BNC;++c){
        if constexpr (BCW == 4) {
          float4 v = *(const float4*)&Bs[kk*SB + c*BR + tx*4];
          bf[c*4+0]=v.x; bf[c*4+1]=v.y; bf[c*4+2]=v.z; bf[c*4+3]=v.w;
        } else {
          float2 v = *(const float2*)&Bs[kk*SB + c*BR + tx*2];
          bf[c*2+0]=v.x; bf[c*2+1]=v.y;
        }
      }
#pragma unroll
      for (int i=0;i<TM;++i)
#pragma unroll
        for (int j=0;j<TN;++j) acc[i][j]=fmaf(af[i],bf[j],acc[i][j]);
    }
  }
}

// ---------------- GX + GH in one launch (blockIdx.z selects), 64x64/TM4 -----
__global__ __launch_bounds__(256) void gemm_gxgh_kernel(
    const float* __restrict__ PREV, const float* __restrict__ H,
    const float* __restrict__ Wih, const float* __restrict__ Whh,
    const float* __restrict__ bih, const float* __restrict__ bhh,
    float* __restrict__ GX, float* __restrict__ GH)
{
  __shared__ float As[16*(64+4)];
  __shared__ float Bs[16*(64+4)];
  const int z = blockIdx.z;
  const float* A   = z ? H   : PREV;
  const float* B   = z ? Whh : Wih;
  const float* bia = z ? bhh : bih;
  float* C         = z ? GH  : GX;
  const int lda    = z ? HD  : DDIM;   // == K
  const int m0 = blockIdx.x * 64, n0 = blockIdx.y * 64;
  float acc[4][4] = {};
  gemm_engine<64,64,16,4,4>(A, lda, B, lda, lda, m0, n0, threadIdx.x, As, Bs, acc);
  {
#pragma clang fp contract(off)
    const int tx = threadIdx.x & 15, ty = threadIdx.x >> 4;
#pragma unroll
    for (int i = 0; i < 4; ++i)
#pragma unroll
      for (int j = 0; j < 4; ++j)
        C[(size_t)(m0 + ty*4 + i) * G3 + n0 + tx*4 + j] = acc[i][j] + bia[n0 + tx*4 + j];
  }
}

// ---------------- GB gemm with fused FiLM epilogue (interleaved W), 32x64 ---
__global__ __launch_bounds__(256) void gemm_gb_film_kernel(
    const float* __restrict__ H, const float* __restrict__ W,
    const float* __restrict__ bv, const float* __restrict__ SM,
    float* __restrict__ PIN)
{
  __shared__ float As[32*(32+4)];
  __shared__ float Bs[32*(64+4)];
  const int m0 = blockIdx.x * 32, n0 = blockIdx.y * 64;
  float acc[2][4] = {};
  gemm_engine<32,64,32,2,4>(H, HD, W, HD, HD, m0, n0, threadIdx.x, As, Bs, acc);
  {
#pragma clang fp contract(off)
    const int tx = threadIdx.x & 15, ty = threadIdx.x >> 4;
    const int cb0 = n0 + tx * 4;            // even; pairs (gamma,beta) per channel
#pragma unroll
    for (int i = 0; i < 2; ++i) {
      const int row = m0 + ty*2 + i;
#pragma unroll
      for (int p = 0; p < 2; ++p) {
        float g  = acc[i][2*p]   + bv[cb0 + 2*p];      // gamma = h@Wg.T + bg
        float be = acc[i][2*p+1] + bv[cb0 + 2*p + 1];  // beta  = h@Wb.T + bb
        const int ch = (cb0 >> 1) + p;
        float t1 = 1.0f + g;
        float t2 = t1 * SM[(size_t)row * CDIM + ch];
        PIN[(size_t)row * 1024 + 512 + ch] = t2 + be;
      }
    }
  }
}

// ---------------- MLP gemms (templated tile) --------------------------------
template<bool RELU,int BM,int BN,int BK,int TM,int TN>
__global__ __launch_bounds__(256) void gemm_mlp_kernel(
    const float* __restrict__ A, int lda,
    const float* __restrict__ B,
    const float* __restrict__ bias, int K, int N, float* __restrict__ C)
{
  __shared__ float As[BK*(BM+4)];
  __shared__ float Bs[BK*(BN+4)];
  const int m0 = blockIdx.x * BM, n0 = blockIdx.y * BN;
  float acc[TM][TN] = {};
  gemm_engine<BM,BN,BK,TM,TN>(A, lda, B, K, K, m0, n0, threadIdx.x, As, Bs, acc);
  {
#pragma clang fp contract(off)
    constexpr int ACW = (TM % 4 == 0) ? 4 : 2;
    constexpr int BCW = (TN % 4 == 0) ? 4 : 2;
    constexpr int AR  = BM/(TM/ACW);
    constexpr int BR  = BN/(TN/BCW);
    const int tx = threadIdx.x % (BN/TN), ty = threadIdx.x / (BN/TN);
#pragma unroll
    for (int i = 0; i < TM; ++i) {
      const int row = m0 + (i/ACW)*AR + ty*ACW + (i%ACW);
#pragma unroll
      for (int j = 0; j < TN; ++j) {
        const int col = n0 + (j/BCW)*BR + tx*BCW + (j%BCW);
        float v = acc[i][j] + bias[col];
        if (RELU) v = fmaxf(v, 0.0f);
        C[(size_t)row * N + col] = v;
      }
    }
  }
}

// --------- VQ: proven 64x64/TM4xTN4 single-buffer + shuffle min-butterfly ---
// d = (szz - 2G) + scb; 16-lane __shfl_xor min; one atomicMin per row.
__global__ __launch_bounds__(256) void gemm_score_argmin(
    const float* __restrict__ Z,      // z [B,D]
    const float* __restrict__ CBm,    // cb [K,D]
    const float* __restrict__ cbsq,   // [K]
    const float* __restrict__ szz,    // [B]
    unsigned long long* __restrict__ rowkeys)
{
  __shared__ float As[16*(64+4)];
  __shared__ float Bs[16*(64+4)];
  const int tid = threadIdx.x;
  const int m0 = blockIdx.x * 64, n0 = blockIdx.y * 64;
  float acc[4][4] = {};
  gemm_engine<64,64,16,4,4>(Z, DDIM, CBm, DDIM, DDIM, m0, n0, tid, As, Bs, acc);
  {
#pragma clang fp contract(off)
    const int tx = tid & 15, ty = tid >> 4;
    const int nb = n0 + tx * 4;
#pragma unroll
    for (int i = 0; i < 4; ++i) {
      const int row = ty*4 + i;
      const float sz = szz[m0 + row];
      unsigned long long kb[4];
#pragma unroll
      for (int j = 0; j < 4; ++j) {
        float g2 = 2.0f * acc[i][j];     // exact (pow2 scale)
        float t1 = sz - g2;              // np: (szz - 2G)
        float d  = t1 + cbsq[nb + j];    // np: ... + scb
        kb[j] = key32(d, nb + j);
      }
      unsigned long long a0 = kb[0] < kb[1] ? kb[0] : kb[1];
      unsigned long long a1 = kb[2] < kb[3] ? kb[2] : kb[3];
      unsigned long long best = a0 < a1 ? a0 : a1;
      // min across the 16 lanes sharing ty (tx group); masks < 16 stay in-group
#pragma unroll
      for (int mask = 1; mask < 16; mask <<= 1) {
        unsigned long long o = __shfl_xor(best, mask);
        best = o < best ? o : best;
      }
      if (tx == 0) atomicMin(&rowkeys[m0 + row], best);
    }
  }
}

// ---------------- elementwise / reduction kernels (np-f32 faithful) ---------
// 16 lanes per row; exact numpy pw256 tree via commutative shuffle combine.
__global__ __launch_bounds__(256) void pw256_rows_kernel(const float* __restrict__ src,
                                                         float* __restrict__ dst,
                                                         int square) {
#pragma clang fp contract(off)
  int gid = blockIdx.x * 256 + threadIdx.x;
  int row = gid >> 4;
  int l = gid & 15;                       // h = l>>3 (half), j = l&7 (chain)
  const float* a = src + (size_t)row * 256 + ((l >> 3) << 7) + (l & 7);
  float v0 = a[0];
  float r = square ? v0 * v0 : v0;
  for (int i = 1; i < 16; ++i) {
    float w = a[i << 3];
    r += square ? w * w : w;
  }
  float t = r + __shfl_xor(r, 1);         // (r0+r1) ...
  t = t + __shfl_xor(t, 2);               // (r0+r1)+(r2+r3) ...
  t = t + __shfl_xor(t, 4);               // pw128 tree
  float s = t + __shfl_xor(t, 8);         // s0 + s1
  if (l == 0) dst[row] = s;
}

__global__ __launch_bounds__(256) void smean_kernel(const float* __restrict__ sf,
                                                    float* __restrict__ sm) {
#pragma clang fp contract(off)
  int i = blockIdx.x * 256 + threadIdx.x;     // B*C threads
  const float* a = sf + (size_t)i * 49;
  float r0=a[0],r1=a[1],r2=a[2],r3=a[3],r4=a[4],r5=a[5],r6=a[6],r7=a[7];
  for (int k = 8; k < 48; k += 8) {
    r0+=a[k+0]; r1+=a[k+1]; r2+=a[k+2]; r3+=a[k+3];
    r4+=a[k+4]; r5+=a[k+5]; r6+=a[k+6]; r7+=a[k+7];
  }
  float res = ((r0+r1)+(r2+r3))+((r4+r5)+(r6+r7));
  res += a[48];
  sm[i] = res / 49.0f;
}

__global__ __launch_bounds__(256) void previnit_kernel(const float* __restrict__ bos,
                                                       float* __restrict__ prev) {
  int i = blockIdx.x * 256 + threadIdx.x;
  prev[i] = bos[i & (DDIM - 1)];
}

// interleave Wg/Wb rows and bg/bb once per launch
__global__ __launch_bounds__(256) void interleave_film_kernel(
    const float* __restrict__ Wg, const float* __restrict__ Wb,
    const float* __restrict__ bg, const float* __restrict__ bb,
    float* __restrict__ W, float* __restrict__ bv) {
  int i = blockIdx.x * 256 + threadIdx.x;     // 1024*512 elements
  int row = i >> 9, k = i & 511;
  const float* src = (row & 1) ? Wb : Wg;
  W[i] = src[(size_t)(row >> 1) * 512 + k];
  if (i < 1024) bv[i] = ((i & 1) ? bb : bg)[i >> 1];
}

__global__ __launch_bounds__(256) void gru_kernel(const float* __restrict__ gx,
                                                  const float* __restrict__ gh,
                                                  float* __restrict__ h,
                                                  float* __restrict__ pin) {
#pragma clang fp contract(off)
  int i = blockIdx.x * 256 + threadIdx.x;
  int b = i >> 9, j = i & 511;
  size_t o = (size_t)b * G3;
  float xr = gx[o + j], xz = gx[o + 512 + j], xn = gx[o + 1024 + j];
  float hr = gh[o + j], hz = gh[o + 512 + j], hn = gh[o + 1024 + j];
  float ar = xr + hr;
  float az = xz + hz;
  float er = expf(-ar);
  float ez = expf(-az);
  float r  = 1.0f / (1.0f + er);
  float zz = 1.0f / (1.0f + ez);
  float rh = r * hn;
  float an = xn + rh;
  float n  = tanhf(an);
  float hold = h[i];
  float t1 = (1.0f - zz) * n;
  float t2 = zz * hold;
  float hnew = t1 + t2;
  h[i] = hnew;
  pin[(size_t)b * 1024 + j] = hnew;   // left half of pin = h
}

__global__ __launch_bounds__(256) void vq_apply_kernel(
    unsigned long long* __restrict__ rowkeys,
    const float* __restrict__ cb, const float* __restrict__ zbuf,
    float* __restrict__ prev, int* __restrict__ idxarr,
    float* __restrict__ loss_acc, float* __restrict__ out, int t)
{
#pragma clang fp contract(off)
  int b = blockIdx.x, d = threadIdx.x;
  int idx = (int)(rowkeys[b] & 0xFFFFFFFFull);
  float zq = cb[(size_t)idx * DDIM + d];
  float zb = zbuf[(size_t)b * DDIM + d];
  float delta = zq - zb;
  float zste = zb + delta;                  // z + (z_q - z)
  size_t td = ((size_t)b * TSTEPS + t) * DDIM + d;
  out[OUT_CODES + td] = zste;
  out[OUT_ZC + td] = zb;
  prev[(size_t)b * DDIM + d] = zste;
  if (d == 0) {
    idxarr[b] = idx;
    out[OUT_IDX + (size_t)b * TSTEPS + t] = (float)idx;
  }
  float diff = zb - zq;
  __shared__ float red[256];
  red[d] = diff * diff; __syncthreads();
  for (int s = 128; s > 0; s >>= 1) { if (d < s) red[d] += red[d + s]; __syncthreads(); }
  if (d == 0) {
    atomicAdd(loss_acc, red[0]);
    rowkeys[b] = ~0ULL;                     // reset for next step (was a memset)
  }
}

// ---- CSR bucket build + cs EMA chain, fused (both were single-block) -------
__global__ __launch_bounds__(1024) void csr_cs_kernel(const int* __restrict__ idxarr,
                                                      int* __restrict__ list,
                                                      int* __restrict__ base,
                                                      int* __restrict__ cnts,
                                                      float* __restrict__ cs,
                                                      float* __restrict__ nt) {
  __shared__ __align__(16) int sidx[BATCH];
  __shared__ int scnt[KCB];       // 32 KB
  __shared__ int spart[1024];
  __shared__ float scs[KCB];      // 32 KB
  __shared__ float s64v[64];
  const int t = threadIdx.x;
  sidx[t] = idxarr[t];
  for (int i = t; i < KCB; i += 1024) scnt[i] = 0;
  __syncthreads();
  const int my = sidx[t];
  atomicAdd(&scnt[my], 1);
  int rank = 0;
  {
    int b = 0;
    for (; b + 4 <= t; b += 4) {
      int4 v = *(const int4*)&sidx[b];
      rank += (v.x == my) + (v.y == my) + (v.z == my) + (v.w == my);
    }
    for (; b < t; ++b) rank += (sidx[b] == my) ? 1 : 0;
  }
  __syncthreads();
  const int c0 = t * 8;
  int loc[8]; int s0 = 0;
#pragma unroll
  for (int i = 0; i < 8; ++i) { loc[i] = s0; s0 += scnt[c0 + i]; }
  spart[t] = s0;
  __syncthreads();
  // parallel inclusive scan (integer, exact), then convert to exclusive
  for (int off = 1; off < 1024; off <<= 1) {
    int v = (t >= off) ? spart[t - off] : 0;
    __syncthreads();
    spart[t] += v;
    __syncthreads();
  }
  {
    int incl = spart[t];
    __syncthreads();
    spart[t] = incl - s0;       // exclusive base
    __syncthreads();
  }
  const int off = spart[t];
#pragma unroll
  for (int i = 0; i < 8; ++i) { base[c0 + i] = off + loc[i]; cnts[c0 + i] = scnt[c0 + i]; }
  const int kb = my >> 3, kr = my & 7;
  int bb = spart[kb];
  for (int i = 0; i < kr; ++i) bb += scnt[(kb << 3) + i];
  list[bb + rank] = t;

  // ---- cs chain (exact op order preserved from cs_fused_kernel) ----
  {
#pragma clang fp contract(off)
    for (int i = t; i < KCB; i += 1024) {
      float a = 0.99f * cs[i];
      float b2 = 0.01f * (float)scnt[i];
      scs[i] = a + b2;
    }
    __syncthreads();
    if (t < 64) s64v[t] = pw128(scs + t * 128);
    __syncthreads();
    if (t == 0) {
      float v[64];
      for (int i = 0; i < 64; ++i) v[i] = s64v[i];
      for (int len = 64; len > 1; len >>= 1)
        for (int i = 0; i < (len >> 1); ++i) v[i] = v[2*i] + v[2*i+1];
      nt[0] = v[0];
      s64v[0] = v[0];
    }
    __syncthreads();
    const float n = s64v[0];
    const float den = n + 0.08192f;          // f32(K*EPS)
    for (int i = t; i < KCB; i += 1024) {
      float t1 = scs[i] + 1e-5f;
      float q = t1 / den;
      cs[i] = q * n;
    }
  }
}

// ---- EMA fused: 8 rows/block; gather with 16-deep load batching -------------
__global__ __launch_bounds__(256) void ema_fused_kernel(
    float* __restrict__ ew, const int* __restrict__ list,
    const int* __restrict__ base, const int* __restrict__ cnts,
    const float* __restrict__ zbuf, const float* __restrict__ cs,
    float* __restrict__ cb, float* __restrict__ cbsq)
{
#pragma clang fp contract(off)
  __shared__ float row2[256];
  __shared__ float ch[16];
  const int d = threadIdx.x;
  for (int r = 0; r < 8; ++r) {
    const int k = blockIdx.x * 8 + r;
    const int start = base[k], cnt = cnts[k];
    float acc = 0.0f;
    int i = 0;
    for (; i + 16 <= cnt; i += 16) {
      int bi[16];
#pragma unroll
      for (int u = 0; u < 16; ++u) bi[u] = list[start + i + u];
      float v[16];
#pragma unroll
      for (int u = 0; u < 16; ++u) v[u] = zbuf[(size_t)bi[u] * DDIM + d];
#pragma unroll
      for (int u = 0; u < 16; ++u) acc += v[u];   // exact ascending-b order
    }
    for (; i < cnt; ++i) {
      acc += zbuf[(size_t)list[start + i] * DDIM + d];
    }
    const size_t o = (size_t)k * DDIM + d;
    float a = 0.99f * ew[o];
    float bb = 0.01f * acc;
    float e = a + bb;
    ew[o] = e;
    float c = e / cs[k];
    cb[o] = c;
    row2[d] = c * c;
    __syncthreads();
    if (d < 16) {
      int h = d >> 3, j = d & 7;
      const float* p = row2 + h * 128 + j;
      float rr = p[0];
      for (int i2 = 1; i2 < 16; ++i2) rr += p[8 * i2];
      ch[d] = rr;
    }
    __syncthreads();
    if (d == 0) {
      float s0 = ((ch[0]+ch[1])+(ch[2]+ch[3]))+((ch[4]+ch[5])+(ch[6]+ch[7]));
      float s1 = ((ch[8]+ch[9])+(ch[10]+ch[11]))+((ch[12]+ch[13])+(ch[14]+ch[15]));
      cbsq[k] = s0 + s1;
    }
    __syncthreads();
  }
}

__global__ __launch_bounds__(256) void hfinal_kernel(const float* __restrict__ h,
                                                     float* __restrict__ out) {
  int i = blockIdx.x * 256 + threadIdx.x;
  out[OUT_HF + i] = h[i];
}

__global__ void loss_kernel(const float* __restrict__ loss_acc,
                            float* __restrict__ out) {
  out[OUT_LOSS] = 0.25f * (*loss_acc) / ((float)(BATCH * DDIM)) / (float)TSTEPS;
}

// ---------------- launch ----------------
extern "C" void kernel_launch(void* const* d_in, const int* in_sizes, int n_in,
                              void* d_out, int out_size, void* d_ws, size_t ws_size,
                              hipStream_t stream) {
  const float* sf    = (const float*)d_in[0];
  const float* bos   = (const float*)d_in[1];
  const float* W_ih  = (const float*)d_in[2];
  const float* W_hh  = (const float*)d_in[3];
  const float* b_ih  = (const float*)d_in[4];
  const float* b_hh  = (const float*)d_in[5];
  const float* Wg    = (const float*)d_in[6];
  const float* bg    = (const float*)d_in[7];
  const float* Wb    = (const float*)d_in[8];
  const float* bb    = (const float*)d_in[9];
  const float* W1    = (const float*)d_in[10];
  const float* b1    = (const float*)d_in[11];
  const float* W2    = (const float*)d_in[12];
  const float* b2    = (const float*)d_in[13];
  const float* cb_in = (const float*)d_in[14];
  const float* cs_in = (const float*)d_in[15];
  const float* ew_in = (const float*)d_in[16];

  float* ws  = (float*)d_ws;
  float* out = (float*)d_out;

  float* CB   = ws + WS_CB;
  float* EW   = ws + WS_EW;
  int*   LIST = (int*)(ws + WS_CSR);
  int*   BASE = LIST + BATCH;
  int*   CNTS = BASE + KCB;
  float* SM   = ws + WS_SM;
  float* H    = ws + WS_H;
  float* PREV = ws + WS_PREV;
  float* Z    = ws + WS_Z;
  float* GX   = ws + WS_GX;
  float* GH   = ws + WS_GH;
  float* PIN  = ws + WS_PIN;
  float* H1   = ws + WS_H1;
  float* CS   = ws + WS_CS;
  float* CBSQ = ws + WS_CBSQ;
  float* SZZ  = ws + WS_SZZ;
  float* NT   = ws + WS_NT;
  float* LOSS = ws + WS_LOSS;
  int*   IDX  = (int*)(ws + WS_IDX);
  unsigned long long* ROWK = (unsigned long long*)(ws + WS_ROWK);
  float* WGWB = ws + WS_WGWB;
  float* BGBB = ws + WS_BGBB;

  // ---- per-launch init ----
  (void)hipMemcpyAsync(CB, cb_in, (size_t)KCB * DDIM * 4, hipMemcpyDeviceToDevice, stream);
  (void)hipMemcpyAsync(EW, ew_in, (size_t)KCB * DDIM * 4, hipMemcpyDeviceToDevice, stream);
  (void)hipMemcpyAsync(CS, cs_in, (size_t)KCB * 4, hipMemcpyDeviceToDevice, stream);
  interleave_film_kernel<<<(1024*512)/256, 256, 0, stream>>>(Wg, Wb, bg, bb, WGWB, BGBB);
  (void)hipMemsetAsync(H, 0, (size_t)BATCH * HD * 4, stream);
  (void)hipMemsetAsync(LOSS, 0, 8, stream);
  (void)hipMemsetAsync(ROWK, 0xFF, BATCH * 8, stream);
  previnit_kernel<<<BATCH * DDIM / 256, 256, 0, stream>>>(bos, PREV);
  smean_kernel<<<BATCH * CDIM / 256, 256, 0, stream>>>(sf, SM);
  pw256_rows_kernel<<<(KCB * 16) / 256, 256, 0, stream>>>(CB, CBSQ, 1);

  for (int t = 0; t < TSTEPS; ++t) {
    // GRU gates (GX and GH in one launch for CU coverage)
    gemm_gxgh_kernel<<<dim3(BATCH/64, G3/64, 2), 256, 0, stream>>>(
        PREV, H, W_ih, W_hh, b_ih, b_hh, GX, GH);
    gru_kernel<<<BATCH * HD / 256, 256, 0, stream>>>(GX, GH, H, PIN);

    // FiLM fused into GB epilogue (writes pin right half)
    gemm_gb_film_kernel<<<dim3(BATCH/32, 1024/64), 256, 0, stream>>>(H, WGWB, BGBB, SM, PIN);

    // MLP
    gemm_mlp_kernel<true, 64,32,32,4,2><<<dim3(BATCH/64, HD/32),   256, 0, stream>>>(PIN, 1024, W1, b1, 1024, HD, H1);
    gemm_mlp_kernel<false,32,32,32,2,2><<<dim3(BATCH/32, DDIM/32), 256, 0, stream>>>(H1, HD, W2, b2, HD, DDIM, Z);

    // VQ
    pw256_rows_kernel<<<(BATCH * 16) / 256, 256, 0, stream>>>(Z, SZZ, 1);
    gemm_score_argmin<<<dim3(BATCH/64, KCB/64), 256, 0, stream>>>(Z, CB, CBSQ, SZZ, ROWK);
    vq_apply_kernel<<<BATCH, 256, 0, stream>>>(ROWK, CB, Z, PREV, IDX, LOSS, out, t);

    // EMA via CSR (deterministic np.add.at order), cs chain fused in
    csr_cs_kernel<<<1, 1024, 0, stream>>>(IDX, LIST, BASE, CNTS, CS, NT);
    ema_fused_kernel<<<KCB/8, 256, 0, stream>>>(EW, LIST, BASE, CNTS, Z, CS, CB, CBSQ);
  }

  hfinal_kernel<<<BATCH * HD / 256, 256, 0, stream>>>(H, out);
  loss_kernel<<<1, 1, 0, stream>>>(LOSS, out);
}

// Round 6
// 2043.698 us; speedup vs baseline: 1.1263x; 1.1263x over previous
//
#include <hip/hip_runtime.h>

#define BATCH 1024
#define CDIM  512
#define DDIM  256
#define KCB   8192
#define HD    512
#define G3    1536
#define TSTEPS 8

// ---------------- workspace layout (float offsets) ----------------
#define WS_CB    ((size_t)0)          // [K,D]
#define WS_EW    ((size_t)2097152)    // [K,D]
#define WS_CSR   ((size_t)4194304)    // ints: list[1024] | base[8192] | cnts[8192]
#define WS_SM    ((size_t)6291456)    // [B,C]
#define WS_H     ((size_t)6815744)    // [B,HD]
#define WS_PREV  ((size_t)7340032)    // [B,D]
#define WS_Z     ((size_t)7602176)    // [B,D]
#define WS_GX    ((size_t)7864320)    // [B,3HD]
#define WS_GH    ((size_t)9437184)    // [B,3HD]
#define WS_PIN   ((size_t)12058624)   // [B,1024]
#define WS_H1    ((size_t)13107200)   // [B,HD]
#define WS_CS    ((size_t)13631488)   // [K]
#define WS_CBSQ  ((size_t)13639680)   // [K]
#define WS_SZZ   ((size_t)13647872)   // [B]
#define WS_NT    ((size_t)13657088)   // [1]+pad
#define WS_LOSS  ((size_t)13657090)   // [1]+pad
#define WS_IDX   ((size_t)13657092)   // [B] ints
#define WS_ROWK  ((size_t)13658116)   // [B] u64 (8B-aligned)
#define WS_WGWB  ((size_t)13660164)   // [1024,512] interleaved (Wg[c],Wb[c]) rows
#define WS_BGBB  ((size_t)14184452)   // [1024] interleaved (bg[c],bb[c])

// ---------------- output layout (f32 elements) ----------------
#define OUT_HF    ((size_t)0)
#define OUT_CODES ((size_t)524288)
#define OUT_IDX   ((size_t)2621440)
#define OUT_ZC    ((size_t)2629632)
#define OUT_LOSS  ((size_t)4726784)

// order-preserving map of f32 bits; col in low 32 bits -> ties pick lowest col
static __device__ __forceinline__ unsigned long long key32(float s, int col) {
  unsigned int u = __float_as_uint(s);
  u = (u & 0x80000000u) ? ~u : (u | 0x80000000u);
  return (((unsigned long long)u) << 32) | (unsigned long long)(unsigned int)col;
}

// numpy pairwise_sum for n=128 block: 8 accumulators, tree combine
static __device__ __forceinline__ float pw128(const float* a) {
  float r0=a[0],r1=a[1],r2=a[2],r3=a[3],r4=a[4],r5=a[5],r6=a[6],r7=a[7];
  for (int i = 8; i < 128; i += 8) {
    r0+=a[i+0]; r1+=a[i+1]; r2+=a[i+2]; r3+=a[i+3];
    r4+=a[i+4]; r5+=a[i+5]; r6+=a[i+6]; r7+=a[i+7];
  }
  return ((r0+r1)+(r2+r3))+((r4+r5)+(r6+r7));
}

// ============================================================================
// Double-buffered fp32 GEMM engine with CHUNKED fragments — used for the
// MID-size GEMMs (few blocks, latency-bound): r4-vs-r5 A/B showed dbuf is
// ~200us/launch-set better there. NOT used for the score GEMM (see below).
// Per output element: fmaf chain in ascending-k order over the FULL K.
// ============================================================================
template<int BM,int BN,int BK,int TM,int TN>
__device__ __forceinline__ void gemm_engine(
    const float* __restrict__ A, int lda,
    const float* __restrict__ B, int ldb, int K,
    int m0, int n0, int tid,
    float* __restrict__ As, float* __restrict__ Bs,
    float (&acc)[TM][TN])
{
  constexpr int NT = 256;
  constexpr int K4 = BK/4;
  constexpr int LA = (BM*BK)/(4*NT);
  constexpr int LB = (BN*BK)/(4*NT);
  constexpr int SA = BM+4;
  constexpr int SB = BN+4;
  constexpr int ACW = (TM % 4 == 0) ? 4 : 2;
  constexpr int BCW = (TN % 4 == 0) ? 4 : 2;
  constexpr int ANC = TM/ACW;
  constexpr int BNC = TN/BCW;
  constexpr int AR  = BM/ANC;     // row offset between A chunks
  constexpr int BR  = BN/BNC;     // col offset between B chunks
  static_assert((BM/TM)*(BN/TN) == NT, "256 threads");
  static_assert(LA >= 1 && LB >= 1, "stage width");

  const int tx = tid % (BN/TN);
  const int ty = tid / (BN/TN);

  int arow[LA], ak4[LA], brow[LB], bk4[LB];
#pragma unroll
  for (int l=0;l<LA;++l){ int f=l*NT+tid; arow[l]=f/K4; ak4[l]=f%K4; }
#pragma unroll
  for (int l=0;l<LB;++l){ int f=l*NT+tid; brow[l]=f/K4; bk4[l]=f%K4; }

  float4 ra[LA], rb[LB];
  // prologue: tile 0 -> buf 0
#pragma unroll
  for (int l=0;l<LA;++l) ra[l] = *(const float4*)(A + (size_t)(m0+arow[l])*lda + ak4[l]*4);
#pragma unroll
  for (int l=0;l<LB;++l) rb[l] = *(const float4*)(B + (size_t)(n0+brow[l])*ldb + bk4[l]*4);
#pragma unroll
  for (int l=0;l<LA;++l){ int kb=ak4[l]*4, r=arow[l];
    As[(kb+0)*SA+r]=ra[l].x; As[(kb+1)*SA+r]=ra[l].y; As[(kb+2)*SA+r]=ra[l].z; As[(kb+3)*SA+r]=ra[l].w; }
#pragma unroll
  for (int l=0;l<LB;++l){ int kb=bk4[l]*4, r=brow[l];
    Bs[(kb+0)*SB+r]=rb[l].x; Bs[(kb+1)*SB+r]=rb[l].y; Bs[(kb+2)*SB+r]=rb[l].z; Bs[(kb+3)*SB+r]=rb[l].w; }
  __syncthreads();

  int cur = 0;
  for (int k0 = BK; k0 < K; k0 += BK) {
    // prefetch next tile to registers (latency hidden under compute below)
#pragma unroll
    for (int l=0;l<LA;++l) ra[l] = *(const float4*)(A + (size_t)(m0+arow[l])*lda + k0 + ak4[l]*4);
#pragma unroll
    for (int l=0;l<LB;++l) rb[l] = *(const float4*)(B + (size_t)(n0+brow[l])*ldb + k0 + bk4[l]*4);
    // compute current buffer
    {
      const float* as = As + cur*(BK*SA);
      const float* bs = Bs + cur*(BK*SB);
#pragma unroll
      for (int kk=0;kk<BK;++kk){
        float af[TM], bf[TN];
#pragma unroll
        for (int c=0;c<ANC;++c){
          if constexpr (ACW == 4) {
            float4 v = *(const float4*)&as[kk*SA + c*AR + ty*4];
            af[c*4+0]=v.x; af[c*4+1]=v.y; af[c*4+2]=v.z; af[c*4+3]=v.w;
          } else {
            float2 v = *(const float2*)&as[kk*SA + c*AR + ty*2];
            af[c*2+0]=v.x; af[c*2+1]=v.y;
          }
        }
#pragma unroll
        for (int c=0;c<BNC;++c){
          if constexpr (BCW == 4) {
            float4 v = *(const float4*)&bs[kk*SB + c*BR + tx*4];
            bf[c*4+0]=v.x; bf[c*4+1]=v.y; bf[c*4+2]=v.z; bf[c*4+3]=v.w;
          } else {
            float2 v = *(const float2*)&bs[kk*SB + c*BR + tx*2];
            bf[c*2+0]=v.x; bf[c*2+1]=v.y;
          }
        }
#pragma unroll
        for (int i=0;i<TM;++i)
#pragma unroll
          for (int j=0;j<TN;++j) acc[i][j]=fmaf(af[i],bf[j],acc[i][j]);
      }
    }
    // store prefetched tile into the other buffer
    {
      float* as = As + (cur^1)*(BK*SA);
      float* bs = Bs + (cur^1)*(BK*SB);
#pragma unroll
      for (int l=0;l<LA;++l){ int kb=ak4[l]*4, r=arow[l];
        as[(kb+0)*SA+r]=ra[l].x; as[(kb+1)*SA+r]=ra[l].y; as[(kb+2)*SA+r]=ra[l].z; as[(kb+3)*SA+r]=ra[l].w; }
#pragma unroll
      for (int l=0;l<LB;++l){ int kb=bk4[l]*4, r=brow[l];
        bs[(kb+0)*SB+r]=rb[l].x; bs[(kb+1)*SB+r]=rb[l].y; bs[(kb+2)*SB+r]=rb[l].z; bs[(kb+3)*SB+r]=rb[l].w; }
    }
    __syncthreads();
    cur ^= 1;
  }
  // final tile
  {
    const float* as = As + cur*(BK*SA);
    const float* bs = Bs + cur*(BK*SB);
#pragma unroll
    for (int kk=0;kk<BK;++kk){
      float af[TM], bf[TN];
#pragma unroll
      for (int c=0;c<ANC;++c){
        if constexpr (ACW == 4) {
          float4 v = *(const float4*)&as[kk*SA + c*AR + ty*4];
          af[c*4+0]=v.x; af[c*4+1]=v.y; af[c*4+2]=v.z; af[c*4+3]=v.w;
        } else {
          float2 v = *(const float2*)&as[kk*SA + c*AR + ty*2];
          af[c*2+0]=v.x; af[c*2+1]=v.y;
        }
      }
#pragma unroll
      for (int c=0;c<BNC;++c){
        if constexpr (BCW == 4) {
          float4 v = *(const float4*)&bs[kk*SB + c*BR + tx*4];
          bf[c*4+0]=v.x; bf[c*4+1]=v.y; bf[c*4+2]=v.z; bf[c*4+3]=v.w;
        } else {
          float2 v = *(const float2*)&bs[kk*SB + c*BR + tx*2];
          bf[c*2+0]=v.x; bf[c*2+1]=v.y;
        }
      }
#pragma unroll
      for (int i=0;i<TM;++i)
#pragma unroll
        for (int j=0;j<TN;++j) acc[i][j]=fmaf(af[i],bf[j],acc[i][j]);
    }
  }
}

// ---------------- GX + GH in one launch (blockIdx.z selects), 64x64/TM4 -----
__global__ __launch_bounds__(256) void gemm_gxgh_kernel(
    const float* __restrict__ PREV, const float* __restrict__ H,
    const float* __restrict__ Wih, const float* __restrict__ Whh,
    const float* __restrict__ bih, const float* __restrict__ bhh,
    float* __restrict__ GX, float* __restrict__ GH)
{
  __shared__ float As[2*16*(64+4)];
  __shared__ float Bs[2*16*(64+4)];
  const int z = blockIdx.z;
  const float* A   = z ? H   : PREV;
  const float* B   = z ? Whh : Wih;
  const float* bia = z ? bhh : bih;
  float* C         = z ? GH  : GX;
  const int lda    = z ? HD  : DDIM;   // == K
  const int m0 = blockIdx.x * 64, n0 = blockIdx.y * 64;
  float acc[4][4] = {};
  gemm_engine<64,64,16,4,4>(A, lda, B, lda, lda, m0, n0, threadIdx.x, As, Bs, acc);
  {
#pragma clang fp contract(off)
    const int tx = threadIdx.x & 15, ty = threadIdx.x >> 4;
#pragma unroll
    for (int i = 0; i < 4; ++i)
#pragma unroll
      for (int j = 0; j < 4; ++j)
        C[(size_t)(m0 + ty*4 + i) * G3 + n0 + tx*4 + j] = acc[i][j] + bia[n0 + tx*4 + j];
  }
}

// ---------------- GB gemm with fused FiLM epilogue (interleaved W), 32x64 ---
__global__ __launch_bounds__(256) void gemm_gb_film_kernel(
    const float* __restrict__ H, const float* __restrict__ W,
    const float* __restrict__ bv, const float* __restrict__ SM,
    float* __restrict__ PIN)
{
  __shared__ float As[2*32*(32+4)];
  __shared__ float Bs[2*32*(64+4)];
  const int m0 = blockIdx.x * 32, n0 = blockIdx.y * 64;
  float acc[2][4] = {};
  gemm_engine<32,64,32,2,4>(H, HD, W, HD, HD, m0, n0, threadIdx.x, As, Bs, acc);
  {
#pragma clang fp contract(off)
    const int tx = threadIdx.x & 15, ty = threadIdx.x >> 4;
    const int cb0 = n0 + tx * 4;            // even; pairs (gamma,beta) per channel
#pragma unroll
    for (int i = 0; i < 2; ++i) {
      const int row = m0 + ty*2 + i;
#pragma unroll
      for (int p = 0; p < 2; ++p) {
        float g  = acc[i][2*p]   + bv[cb0 + 2*p];      // gamma = h@Wg.T + bg
        float be = acc[i][2*p+1] + bv[cb0 + 2*p + 1];  // beta  = h@Wb.T + bb
        const int ch = (cb0 >> 1) + p;
        float t1 = 1.0f + g;
        float t2 = t1 * SM[(size_t)row * CDIM + ch];
        PIN[(size_t)row * 1024 + 512 + ch] = t2 + be;
      }
    }
  }
}

// ---------------- MLP gemms (templated tile) --------------------------------
template<bool RELU,int BM,int BN,int BK,int TM,int TN>
__global__ __launch_bounds__(256) void gemm_mlp_kernel(
    const float* __restrict__ A, int lda,
    const float* __restrict__ B,
    const float* __restrict__ bias, int K, int N, float* __restrict__ C)
{
  __shared__ float As[2*BK*(BM+4)];
  __shared__ float Bs[2*BK*(BN+4)];
  const int m0 = blockIdx.x * BM, n0 = blockIdx.y * BN;
  float acc[TM][TN] = {};
  gemm_engine<BM,BN,BK,TM,TN>(A, lda, B, K, K, m0, n0, threadIdx.x, As, Bs, acc);
  {
#pragma clang fp contract(off)
    constexpr int ACW = (TM % 4 == 0) ? 4 : 2;
    constexpr int BCW = (TN % 4 == 0) ? 4 : 2;
    constexpr int AR  = BM/(TM/ACW);
    constexpr int BR  = BN/(TN/BCW);
    const int tx = threadIdx.x % (BN/TN), ty = threadIdx.x / (BN/TN);
#pragma unroll
    for (int i = 0; i < TM; ++i) {
      const int row = m0 + (i/ACW)*AR + ty*ACW + (i%ACW);
#pragma unroll
      for (int j = 0; j < TN; ++j) {
        const int col = n0 + (j/BCW)*BR + tx*BCW + (j%BCW);
        float v = acc[i][j] + bias[col];
        if (RELU) v = fmaxf(v, 0.0f);
        C[(size_t)row * N + col] = v;
      }
    }
  }
}

// --------- VQ score+argmin: EXACT round-0 kernel (measured 64.7us twice).
// Single-buffer 64x64/TM4, 2D As/Bs, Ks-LDS epilogue (parallel writes +
// 64-thread serial min) — beats shuffle-butterfly epilogue by ~5.6us (r5 A/B:
// serial u64 __shfl_xor chains are ds-pipe ops, the LDS tree issues cheaper).
__global__ __launch_bounds__(256) void gemm_score_argmin(
    const float* __restrict__ A,      // z [B,D]
    const float* __restrict__ Bc,     // cb [K,D]
    const float* __restrict__ cbsq,   // [K]
    const float* __restrict__ szz,    // [B]
    unsigned long long* __restrict__ rowkeys)
{
  __shared__ float As[16][68];
  __shared__ float Bs[16][68];
  __shared__ unsigned long long Ks[64][17];
  const int tid = threadIdx.x;
  const int tx = tid & 15, ty = tid >> 4;
  const int m0 = blockIdx.x * 64, n0 = blockIdx.y * 64;
  const int lr = tid >> 2, lq = tid & 3;
  const float4* Ab = (const float4*)(A + (size_t)(m0 + lr) * DDIM);
  const float4* Bb = (const float4*)(Bc + (size_t)(n0 + lr) * DDIM);
  float acc[4][4] = {};
  for (int k0 = 0; k0 < DDIM; k0 += 16) {
    float4 av = Ab[(k0 >> 2) + lq];
    float4 bv = Bb[(k0 >> 2) + lq];
    __syncthreads();
    As[lq*4+0][lr] = av.x; As[lq*4+1][lr] = av.y;
    As[lq*4+2][lr] = av.z; As[lq*4+3][lr] = av.w;
    Bs[lq*4+0][lr] = bv.x; Bs[lq*4+1][lr] = bv.y;
    Bs[lq*4+2][lr] = bv.z; Bs[lq*4+3][lr] = bv.w;
    __syncthreads();
#pragma unroll
    for (int kk = 0; kk < 16; ++kk) {
      float4 a = *(const float4*)&As[kk][ty*4];
      float4 b = *(const float4*)&Bs[kk][tx*4];
      acc[0][0]=fmaf(a.x,b.x,acc[0][0]); acc[0][1]=fmaf(a.x,b.y,acc[0][1]); acc[0][2]=fmaf(a.x,b.z,acc[0][2]); acc[0][3]=fmaf(a.x,b.w,acc[0][3]);
      acc[1][0]=fmaf(a.y,b.x,acc[1][0]); acc[1][1]=fmaf(a.y,b.y,acc[1][1]); acc[1][2]=fmaf(a.y,b.z,acc[1][2]); acc[1][3]=fmaf(a.y,b.w,acc[1][3]);
      acc[2][0]=fmaf(a.z,b.x,acc[2][0]); acc[2][1]=fmaf(a.z,b.y,acc[2][1]); acc[2][2]=fmaf(a.z,b.z,acc[2][2]); acc[2][3]=fmaf(a.z,b.w,acc[2][3]);
      acc[3][0]=fmaf(a.w,b.x,acc[3][0]); acc[3][1]=fmaf(a.w,b.y,acc[3][1]); acc[3][2]=fmaf(a.w,b.z,acc[3][2]); acc[3][3]=fmaf(a.w,b.w,acc[3][3]);
    }
  }
  {
#pragma clang fp contract(off)
    const int nb = n0 + tx * 4;
#pragma unroll
    for (int i = 0; i < 4; ++i) {
      float sz = szz[m0 + ty*4 + i];
      unsigned long long kb[4];
#pragma unroll
      for (int j = 0; j < 4; ++j) {
        float g2 = 2.0f * acc[i][j];     // exact (pow2 scale)
        float t1 = sz - g2;              // np: (szz - 2G)
        float d  = t1 + cbsq[nb + j];    // np: ... + scb
        kb[j] = key32(d, nb + j);
      }
      unsigned long long ka = kb[0] < kb[1] ? kb[0] : kb[1];
      unsigned long long kc = kb[2] < kb[3] ? kb[2] : kb[3];
      Ks[ty*4 + i][tx] = ka < kc ? ka : kc;
    }
  }
  __syncthreads();
  if (tid < 64) {
    unsigned long long best = Ks[tid][0];
#pragma unroll
    for (int t = 1; t < 16; ++t) {
      unsigned long long v = Ks[tid][t];
      best = v < best ? v : best;
    }
    atomicMin(&rowkeys[m0 + tid], best);
  }
}

// ---------------- elementwise / reduction kernels (np-f32 faithful) ---------
// 16 lanes per row; exact numpy pw256 tree via commutative shuffle combine.
__global__ __launch_bounds__(256) void pw256_rows_kernel(const float* __restrict__ src,
                                                         float* __restrict__ dst,
                                                         int square) {
#pragma clang fp contract(off)
  int gid = blockIdx.x * 256 + threadIdx.x;
  int row = gid >> 4;
  int l = gid & 15;                       // h = l>>3 (half), j = l&7 (chain)
  const float* a = src + (size_t)row * 256 + ((l >> 3) << 7) + (l & 7);
  float v0 = a[0];
  float r = square ? v0 * v0 : v0;
  for (int i = 1; i < 16; ++i) {
    float w = a[i << 3];
    r += square ? w * w : w;
  }
  float t = r + __shfl_xor(r, 1);         // (r0+r1) ...
  t = t + __shfl_xor(t, 2);               // (r0+r1)+(r2+r3) ...
  t = t + __shfl_xor(t, 4);               // pw128 tree
  float s = t + __shfl_xor(t, 8);         // s0 + s1
  if (l == 0) dst[row] = s;
}

__global__ __launch_bounds__(256) void smean_kernel(const float* __restrict__ sf,
                                                    float* __restrict__ sm) {
#pragma clang fp contract(off)
  int i = blockIdx.x * 256 + threadIdx.x;     // B*C threads
  const float* a = sf + (size_t)i * 49;
  float r0=a[0],r1=a[1],r2=a[2],r3=a[3],r4=a[4],r5=a[5],r6=a[6],r7=a[7];
  for (int k = 8; k < 48; k += 8) {
    r0+=a[k+0]; r1+=a[k+1]; r2+=a[k+2]; r3+=a[k+3];
    r4+=a[k+4]; r5+=a[k+5]; r6+=a[k+6]; r7+=a[k+7];
  }
  float res = ((r0+r1)+(r2+r3))+((r4+r5)+(r6+r7));
  res += a[48];
  sm[i] = res / 49.0f;
}

__global__ __launch_bounds__(256) void previnit_kernel(const float* __restrict__ bos,
                                                       float* __restrict__ prev) {
  int i = blockIdx.x * 256 + threadIdx.x;
  prev[i] = bos[i & (DDIM - 1)];
}

// interleave Wg/Wb rows and bg/bb once per launch
__global__ __launch_bounds__(256) void interleave_film_kernel(
    const float* __restrict__ Wg, const float* __restrict__ Wb,
    const float* __restrict__ bg, const float* __restrict__ bb,
    float* __restrict__ W, float* __restrict__ bv) {
  int i = blockIdx.x * 256 + threadIdx.x;     // 1024*512 elements
  int row = i >> 9, k = i & 511;
  const float* src = (row & 1) ? Wb : Wg;
  W[i] = src[(size_t)(row >> 1) * 512 + k];
  if (i < 1024) bv[i] = ((i & 1) ? bb : bg)[i >> 1];
}

__global__ __launch_bounds__(256) void gru_kernel(const float* __restrict__ gx,
                                                  const float* __restrict__ gh,
                                                  float* __restrict__ h,
                                                  float* __restrict__ pin) {
#pragma clang fp contract(off)
  int i = blockIdx.x * 256 + threadIdx.x;
  int b = i >> 9, j = i & 511;
  size_t o = (size_t)b * G3;
  float xr = gx[o + j], xz = gx[o + 512 + j], xn = gx[o + 1024 + j];
  float hr = gh[o + j], hz = gh[o + 512 + j], hn = gh[o + 1024 + j];
  float ar = xr + hr;
  float az = xz + hz;
  float er = expf(-ar);
  float ez = expf(-az);
  float r  = 1.0f / (1.0f + er);
  float zz = 1.0f / (1.0f + ez);
  float rh = r * hn;
  float an = xn + rh;
  float n  = tanhf(an);
  float hold = h[i];
  float t1 = (1.0f - zz) * n;
  float t2 = zz * hold;
  float hnew = t1 + t2;
  h[i] = hnew;
  pin[(size_t)b * 1024 + j] = hnew;   // left half of pin = h
}

__global__ __launch_bounds__(256) void vq_apply_kernel(
    unsigned long long* __restrict__ rowkeys,
    const float* __restrict__ cb, const float* __restrict__ zbuf,
    float* __restrict__ prev, int* __restrict__ idxarr,
    float* __restrict__ loss_acc, float* __restrict__ out, int t)
{
#pragma clang fp contract(off)
  int b = blockIdx.x, d = threadIdx.x;
  int idx = (int)(rowkeys[b] & 0xFFFFFFFFull);
  float zq = cb[(size_t)idx * DDIM + d];
  float zb = zbuf[(size_t)b * DDIM + d];
  float delta = zq - zb;
  float zste = zb + delta;                  // z + (z_q - z)
  size_t td = ((size_t)b * TSTEPS + t) * DDIM + d;
  out[OUT_CODES + td] = zste;
  out[OUT_ZC + td] = zb;
  prev[(size_t)b * DDIM + d] = zste;
  if (d == 0) {
    idxarr[b] = idx;
    out[OUT_IDX + (size_t)b * TSTEPS + t] = (float)idx;
  }
  float diff = zb - zq;
  __shared__ float red[256];
  red[d] = diff * diff; __syncthreads();
  for (int s = 128; s > 0; s >>= 1) { if (d < s) red[d] += red[d + s]; __syncthreads(); }
  if (d == 0) {
    atomicAdd(loss_acc, red[0]);
    rowkeys[b] = ~0ULL;                     // reset for next step (was a memset)
  }
}

// ---- CSR bucket build + cs EMA chain, fused (both were single-block) -------
__global__ __launch_bounds__(1024) void csr_cs_kernel(const int* __restrict__ idxarr,
                                                      int* __restrict__ list,
                                                      int* __restrict__ base,
                                                      int* __restrict__ cnts,
                                                      float* __restrict__ cs,
                                                      float* __restrict__ nt) {
  __shared__ __align__(16) int sidx[BATCH];
  __shared__ int scnt[KCB];       // 32 KB
  __shared__ int spart[1024];
  __shared__ float scs[KCB];      // 32 KB
  __shared__ float s64v[64];
  const int t = threadIdx.x;
  sidx[t] = idxarr[t];
  for (int i = t; i < KCB; i += 1024) scnt[i] = 0;
  __syncthreads();
  const int my = sidx[t];
  atomicAdd(&scnt[my], 1);
  int rank = 0;
  {
    int b = 0;
    for (; b + 4 <= t; b += 4) {
      int4 v = *(const int4*)&sidx[b];
      rank += (v.x == my) + (v.y == my) + (v.z == my) + (v.w == my);
    }
    for (; b < t; ++b) rank += (sidx[b] == my) ? 1 : 0;
  }
  __syncthreads();
  const int c0 = t * 8;
  int loc[8]; int s0 = 0;
#pragma unroll
  for (int i = 0; i < 8; ++i) { loc[i] = s0; s0 += scnt[c0 + i]; }
  spart[t] = s0;
  __syncthreads();
  // parallel inclusive scan (integer, exact), then convert to exclusive
  for (int off = 1; off < 1024; off <<= 1) {
    int v = (t >= off) ? spart[t - off] : 0;
    __syncthreads();
    spart[t] += v;
    __syncthreads();
  }
  {
    int incl = spart[t];
    __syncthreads();
    spart[t] = incl - s0;       // exclusive base
    __syncthreads();
  }
  const int off = spart[t];
#pragma unroll
  for (int i = 0; i < 8; ++i) { base[c0 + i] = off + loc[i]; cnts[c0 + i] = scnt[c0 + i]; }
  const int kb = my >> 3, kr = my & 7;
  int bb = spart[kb];
  for (int i = 0; i < kr; ++i) bb += scnt[(kb << 3) + i];
  list[bb + rank] = t;

  // ---- cs chain (exact op order preserved from cs_fused_kernel) ----
  {
#pragma clang fp contract(off)
    for (int i = t; i < KCB; i += 1024) {
      float a = 0.99f * cs[i];
      float b2 = 0.01f * (float)scnt[i];
      scs[i] = a + b2;
    }
    __syncthreads();
    if (t < 64) s64v[t] = pw128(scs + t * 128);
    __syncthreads();
    if (t == 0) {
      float v[64];
      for (int i = 0; i < 64; ++i) v[i] = s64v[i];
      for (int len = 64; len > 1; len >>= 1)
        for (int i = 0; i < (len >> 1); ++i) v[i] = v[2*i] + v[2*i+1];
      nt[0] = v[0];
      s64v[0] = v[0];
    }
    __syncthreads();
    const float n = s64v[0];
    const float den = n + 0.08192f;          // f32(K*EPS)
    for (int i = t; i < KCB; i += 1024) {
      float t1 = scs[i] + 1e-5f;
      float q = t1 / den;
      cs[i] = q * n;
    }
  }
}

// ---- EMA fused: 8 rows/block; gather with 16-deep load batching -------------
__global__ __launch_bounds__(256) void ema_fused_kernel(
    float* __restrict__ ew, const int* __restrict__ list,
    const int* __restrict__ base, const int* __restrict__ cnts,
    const float* __restrict__ zbuf, const float* __restrict__ cs,
    float* __restrict__ cb, float* __restrict__ cbsq)
{
#pragma clang fp contract(off)
  __shared__ float row2[256];
  __shared__ float ch[16];
  const int d = threadIdx.x;
  for (int r = 0; r < 8; ++r) {
    const int k = blockIdx.x * 8 + r;
    const int start = base[k], cnt = cnts[k];
    float acc = 0.0f;
    int i = 0;
    for (; i + 16 <= cnt; i += 16) {
      int bi[16];
#pragma unroll
      for (int u = 0; u < 16; ++u) bi[u] = list[start + i + u];
      float v[16];
#pragma unroll
      for (int u = 0; u < 16; ++u) v[u] = zbuf[(size_t)bi[u] * DDIM + d];
#pragma unroll
      for (int u = 0; u < 16; ++u) acc += v[u];   // exact ascending-b order
    }
    for (; i < cnt; ++i) {
      acc += zbuf[(size_t)list[start + i] * DDIM + d];
    }
    const size_t o = (size_t)k * DDIM + d;
    float a = 0.99f * ew[o];
    float bb = 0.01f * acc;
    float e = a + bb;
    ew[o] = e;
    float c = e / cs[k];
    cb[o] = c;
    row2[d] = c * c;
    __syncthreads();
    if (d < 16) {
      int h = d >> 3, j = d & 7;
      const float* p = row2 + h * 128 + j;
      float rr = p[0];
      for (int i2 = 1; i2 < 16; ++i2) rr += p[8 * i2];
      ch[d] = rr;
    }
    __syncthreads();
    if (d == 0) {
      float s0 = ((ch[0]+ch[1])+(ch[2]+ch[3]))+((ch[4]+ch[5])+(ch[6]+ch[7]));
      float s1 = ((ch[8]+ch[9])+(ch[10]+ch[11]))+((ch[12]+ch[13])+(ch[14]+ch[15]));
      cbsq[k] = s0 + s1;
    }
    __syncthreads();
  }
}

__global__ __launch_bounds__(256) void hfinal_kernel(const float* __restrict__ h,
                                                     float* __restrict__ out) {
  int i = blockIdx.x * 256 + threadIdx.x;
  out[OUT_HF + i] = h[i];
}

__global__ void loss_kernel(const float* __restrict__ loss_acc,
                            float* __restrict__ out) {
  out[OUT_LOSS] = 0.25f * (*loss_acc) / ((float)(BATCH * DDIM)) / (float)TSTEPS;
}

// ---------------- launch ----------------
extern "C" void kernel_launch(void* const* d_in, const int* in_sizes, int n_in,
                              void* d_out, int out_size, void* d_ws, size_t ws_size,
                              hipStream_t stream) {
  const float* sf    = (const float*)d_in[0];
  const float* bos   = (const float*)d_in[1];
  const float* W_ih  = (const float*)d_in[2];
  const float* W_hh  = (const float*)d_in[3];
  const float* b_ih  = (const float*)d_in[4];
  const float* b_hh  = (const float*)d_in[5];
  const float* Wg    = (const float*)d_in[6];
  const float* bg    = (const float*)d_in[7];
  const float* Wb    = (const float*)d_in[8];
  const float* bb    = (const float*)d_in[9];
  const float* W1    = (const float*)d_in[10];
  const float* b1    = (const float*)d_in[11];
  const float* W2    = (const float*)d_in[12];
  const float* b2    = (const float*)d_in[13];
  const float* cb_in = (const float*)d_in[14];
  const float* cs_in = (const float*)d_in[15];
  const float* ew_in = (const float*)d_in[16];

  float* ws  = (float*)d_ws;
  float* out = (float*)d_out;

  float* CB   = ws + WS_CB;
  float* EW   = ws + WS_EW;
  int*   LIST = (int*)(ws + WS_CSR);
  int*   BASE = LIST + BATCH;
  int*   CNTS = BASE + KCB;
  float* SM   = ws + WS_SM;
  float* H    = ws + WS_H;
  float* PREV = ws + WS_PREV;
  float* Z    = ws + WS_Z;
  float* GX   = ws + WS_GX;
  float* GH   = ws + WS_GH;
  float* PIN  = ws + WS_PIN;
  float* H1   = ws + WS_H1;
  float* CS   = ws + WS_CS;
  float* CBSQ = ws + WS_CBSQ;
  float* SZZ  = ws + WS_SZZ;
  float* NT   = ws + WS_NT;
  float* LOSS = ws + WS_LOSS;
  int*   IDX  = (int*)(ws + WS_IDX);
  unsigned long long* ROWK = (unsigned long long*)(ws + WS_ROWK);
  float* WGWB = ws + WS_WGWB;
  float* BGBB = ws + WS_BGBB;

  // ---- per-launch init ----
  (void)hipMemcpyAsync(CB, cb_in, (size_t)KCB * DDIM * 4, hipMemcpyDeviceToDevice, stream);
  (void)hipMemcpyAsync(EW, ew_in, (size_t)KCB * DDIM * 4, hipMemcpyDeviceToDevice, stream);
  (void)hipMemcpyAsync(CS, cs_in, (size_t)KCB * 4, hipMemcpyDeviceToDevice, stream);
  interleave_film_kernel<<<(1024*512)/256, 256, 0, stream>>>(Wg, Wb, bg, bb, WGWB, BGBB);
  (void)hipMemsetAsync(H, 0, (size_t)BATCH * HD * 4, stream);
  (void)hipMemsetAsync(LOSS, 0, 8, stream);
  (void)hipMemsetAsync(ROWK, 0xFF, BATCH * 8, stream);
  previnit_kernel<<<BATCH * DDIM / 256, 256, 0, stream>>>(bos, PREV);
  smean_kernel<<<BATCH * CDIM / 256, 256, 0, stream>>>(sf, SM);
  pw256_rows_kernel<<<(KCB * 16) / 256, 256, 0, stream>>>(CB, CBSQ, 1);

  for (int t = 0; t < TSTEPS; ++t) {
    // GRU gates (GX and GH in one launch for CU coverage)
    gemm_gxgh_kernel<<<dim3(BATCH/64, G3/64, 2), 256, 0, stream>>>(
        PREV, H, W_ih, W_hh, b_ih, b_hh, GX, GH);
    gru_kernel<<<BATCH * HD / 256, 256, 0, stream>>>(GX, GH, H, PIN);

    // FiLM fused into GB epilogue (writes pin right half)
    gemm_gb_film_kernel<<<dim3(BATCH/32, 1024/64), 256, 0, stream>>>(H, WGWB, BGBB, SM, PIN);

    // MLP
    gemm_mlp_kernel<true, 64,32,32,4,2><<<dim3(BATCH/64, HD/32),   256, 0, stream>>>(PIN, 1024, W1, b1, 1024, HD, H1);
    gemm_mlp_kernel<false,32,32,32,2,2><<<dim3(BATCH/32, DDIM/32), 256, 0, stream>>>(H1, HD, W2, b2, HD, DDIM, Z);

    // VQ
    pw256_rows_kernel<<<(BATCH * 16) / 256, 256, 0, stream>>>(Z, SZZ, 1);
    gemm_score_argmin<<<dim3(BATCH/64, KCB/64), 256, 0, stream>>>(Z, CB, CBSQ, SZZ, ROWK);
    vq_apply_kernel<<<BATCH, 256, 0, stream>>>(ROWK, CB, Z, PREV, IDX, LOSS, out, t);

    // EMA via CSR (deterministic np.add.at order), cs chain fused in
    csr_cs_kernel<<<1, 1024, 0, stream>>>(IDX, LIST, BASE, CNTS, CS, NT);
    ema_fused_kernel<<<KCB/8, 256, 0, stream>>>(EW, LIST, BASE, CNTS, Z, CS, CB, CBSQ);
  }

  hfinal_kernel<<<BATCH * HD / 256, 256, 0, stream>>>(H, out);
  loss_kernel<<<1, 1, 0, stream>>>(LOSS, out);
}